// Round 15
// baseline (212.689 us; speedup 1.0000x reference)
//
#include <hip/hip_runtime.h>

#define NEXP 8
#define DIM  1024
#define HID  2048
#define NTOK 8192

#define BM 128    // gemm2 / fallback tile
#define BN 128
#define BK 32
#define LDK 40    // fallback path: padded LDS stride
#define G1Y 40    // gemm1: y-rows [0,G1Y) = 256-row GEMM tiles (max sum ceil(c/256) = 40)
#define CVTY 16   // y-rows [G1Y, G1Y+CVTY) = w2-cvt tail riders

typedef short s16x8 __attribute__((ext_vector_type(8)));
typedef float f32x4 __attribute__((ext_vector_type(4)));
typedef unsigned short u16;

__device__ __forceinline__ u16 f2bf(float f) {
  unsigned int u = __builtin_bit_cast(unsigned int, f);
  u += 0x7FFFu + ((u >> 16) & 1u);   // RNE
  return (u16)(u >> 16);
}

__device__ __forceinline__ float bf2f(u16 h) {
  unsigned int u = ((unsigned int)h) << 16;
  return __builtin_bit_cast(float, u);
}

__device__ __forceinline__ ushort4 cvt4(float4 a) {
  ushort4 r; r.x = f2bf(a.x); r.y = f2bf(a.y); r.z = f2bf(a.z); r.w = f2bf(a.w); return r;
}

// async global->LDS, 16B per lane; LDS dest must be wave-uniform base (HW adds lane*16)
__device__ __forceinline__ void gload16(const u16* g, u16* l) {
  __builtin_amdgcn_global_load_lds((const __attribute__((address_space(1))) void*)g,
                                   (__attribute__((address_space(3))) void*)l, 16, 0, 0);
}

// Flat row-tile scheduler over the 8 experts (tile height bm). Harness passes counts as int32.
__device__ __forceinline__ bool find_tile(const int* __restrict__ cnts, int rt, int bm,
                                          int& e_out, int& row0, int& cnt_out, long long& off_out) {
  long long off = 0; int cum = 0;
  #pragma unroll
  for (int e = 0; e < NEXP; ++e) {
    int c = cnts[e];
    int nt = (c + bm - 1) / bm;
    if (rt < cum + nt) { e_out = e; row0 = (rt - cum) * bm; cnt_out = c; off_out = off; return true; }
    cum += nt; off += c;
  }
  return false;
}

// ---------------- fp32 -> bf16 conversion: combined flat index, 32-float units ----------------
__device__ __forceinline__ void cvt32(const float* __restrict__ s, u16* __restrict__ d, int j) {
  const float4* p = (const float4*)s + 8 * (size_t)j;
  float4 a[8];
  #pragma unroll
  for (int q = 0; q < 8; ++q) a[q] = p[q];
  s16x8* dst = (s16x8*)d + 4 * (size_t)j;
  #pragma unroll
  for (int q = 0; q < 4; ++q) {
    s16x8 v;
    v[0] = (short)f2bf(a[2*q].x);   v[1] = (short)f2bf(a[2*q].y);
    v[2] = (short)f2bf(a[2*q].z);   v[3] = (short)f2bf(a[2*q].w);
    v[4] = (short)f2bf(a[2*q+1].x); v[5] = (short)f2bf(a[2*q+1].y);
    v[6] = (short)f2bf(a[2*q+1].z); v[7] = (short)f2bf(a[2*q+1].w);
    dst[q] = v;
  }
}

__global__ __launch_bounds__(256) void cvt_multi(
    const float* __restrict__ s0, u16* __restrict__ d0, int n0,
    const float* __restrict__ s1, u16* __restrict__ d1, int n1,
    const float* __restrict__ s2, u16* __restrict__ d2, int n2,
    const float* __restrict__ s3, u16* __restrict__ d3, int n3) {
  const int b0 = n0, b1 = b0 + n1, b2 = b1 + n2, b3 = b2 + n3;
  for (int i = blockIdx.x * blockDim.x + threadIdx.x; i < b3; i += gridDim.x * blockDim.x) {
    if      (i < b0) cvt32(s0, d0, i);
    else if (i < b1) cvt32(s1, d1, i - b0);
    else if (i < b2) cvt32(s2, d2, i - b1);
    else             cvt32(s3, d3, i - b2);
  }
}

// ---------------- GEMM1: 256x128 tile, BK=64, 8 waves, 1 block/CU, 2-buf counted-vmcnt ----------------
// 512 tiles (32 M x 16 N) over 256 slots = 2.0 balanced rounds.
// waves 0-3: gate (w1); waves 4-7: up (w3). Wave sw in [0,4): wr=sw>>1 (128-row half),
// wc=sw&1 (64-col half); per-wave output 128x64 -> acc[8][4] (128 AGPR; budget 256 at 2 waves/SIMD).
// LDS 128KB: A[2][256x64] + B[2][(w1 128 + w3 128) x 64].
// BK=64 swizzle (rows = 128B = 8 x 16B colblks): LDS[row][cb] holds global colblk cb^(row&7);
// gload source colblk cf = (lane&7) ^ ((lane>>3)&7) (involution), ds_read colblk cb^(row&7).
__global__ __launch_bounds__(512, 2) void gemm1_bf16(
    const u16* __restrict__ xb, const int* __restrict__ cnts,
    const u16* __restrict__ w1b, const u16* __restrict__ w3b,
    u16* __restrict__ hbuf,
    const float* __restrict__ w2f, u16* __restrict__ wC, int nW4)
{
  if (blockIdx.y >= G1Y) {
    // w2 fp32->bf16 tail riders: dispatched after all GEMM tiles, backfill tail idle slots
    if (nW4) {
      const int cb = (blockIdx.y - G1Y) * gridDim.x + blockIdx.x;
      const int T  = CVTY * gridDim.x * 512;
      int i = cb * 512 + threadIdx.x;
      const float4* __restrict__ src = (const float4*)w2f;
      ushort4* __restrict__ dst = (ushort4*)wC;
      for (; i + 3 * T < nW4; i += 4 * T) {
        const float4 a0 = src[i];
        const float4 a1 = src[i + T];
        const float4 a2 = src[i + 2 * T];
        const float4 a3 = src[i + 3 * T];
        dst[i]         = cvt4(a0);
        dst[i + T]     = cvt4(a1);
        dst[i + 2 * T] = cvt4(a2);
        dst[i + 3 * T] = cvt4(a3);
      }
      for (; i < nW4; i += T) dst[i] = cvt4(src[i]);
    }
    return;
  }

  int e, row0, cnt; long long off;
  if (!find_tile(cnts, blockIdx.y, 256, e, row0, cnt, off)) return;
  const int ct = blockIdx.x;   // 0..15: output cols ct*128..+127 of HID

  // 128KB union: staging in loop; bf16 up-exchange (4 x 128x72 u16 = 72KB) in epilogue
  __shared__ __align__(16) u16 smem[65536];

  const int t    = threadIdx.x;
  const int lane = t & 63;
  const int wid  = t >> 6;          // 0..7
  const int mat  = wid >> 2;        // 0 = gate/w1, 1 = up/w3
  const int sw   = wid & 3;
  const int wr = sw >> 1, wc = sw & 1;
  const int lr   = lane & 15;
  const int kgrp = lane >> 4;       // 0..3

  // staging lane geometry: within a 1KB chunk (8 rows x 128B), lane covers (row q8, dest colblk cs)
  const int q8 = lane >> 3;         // 0..7
  const int cs = lane & 7;
  const int cf = cs ^ q8;           // source colblk (involution with read-side XOR)

  const u16* xrow = xb + (size_t)(off + row0) * DIM;    // overreads stay inside xb alloc
  const u16* w1t  = w1b + ((size_t)e * HID + (size_t)ct * 128) * DIM;
  const u16* w3t  = w3b + ((size_t)e * HID + (size_t)ct * 128) * DIM;

  f32x4 acc[8][4];
  const f32x4 zf = {0.f, 0.f, 0.f, 0.f};
  #pragma unroll
  for (int i = 0; i < 8; ++i)
    #pragma unroll
    for (int j = 0; j < 4; ++j) acc[i][j] = zf;

  auto STAGE = [&](int k0, int b) {   // 8 gload_lds per wave: A x4, w1 x2, w3 x2
    u16* Ab = smem + b * 16384;
    u16* Bb = smem + 32768 + b * 16384;
    #pragma unroll
    for (int c = 0; c < 4; ++c) {
      const int chunk = wid * 4 + c;            // 0..31
      const int row   = chunk * 8 + q8;         // 0..255
      gload16(&xrow[(size_t)row * DIM + k0 + cf * 8], Ab + chunk * 512);
    }
    #pragma unroll
    for (int c = 0; c < 2; ++c) {
      const int chunk = wid * 2 + c;            // 0..15
      const int row   = chunk * 8 + q8;         // 0..127
      const size_t go = (size_t)row * DIM + k0 + cf * 8;
      gload16(&w1t[go], Bb        + chunk * 512);
      gload16(&w3t[go], Bb + 8192 + chunk * 512);
    }
  };
  auto COMPUTE = [&](int b) {   // 64 MFMA per wave (2 k-slices x 8x4)
    const u16* Ab = smem + b * 16384;
    const u16* Bb = smem + 32768 + b * 16384 + mat * 8192;
    #pragma unroll
    for (int kb = 0; kb < 2; ++kb) {
      const int cb = kb * 4 + kgrp;             // 0..7
      s16x8 af[8], bf[4];
      #pragma unroll
      for (int fm = 0; fm < 8; ++fm) {
        const int row = wr * 128 + fm * 16 + lr;
        af[fm] = *(const s16x8*)&Ab[row * 64 + ((cb ^ (row & 7)) << 3)];
      }
      #pragma unroll
      for (int fn = 0; fn < 4; ++fn) {
        const int row = wc * 64 + fn * 16 + lr;
        bf[fn] = *(const s16x8*)&Bb[row * 64 + ((cb ^ (row & 7)) << 3)];
      }
      #pragma unroll
      for (int fm = 0; fm < 8; ++fm)
        #pragma unroll
        for (int fn = 0; fn < 4; ++fn)
          acc[fm][fn] = __builtin_amdgcn_mfma_f32_16x16x32_bf16(af[fm], bf[fn], acc[fm][fn], 0, 0, 0);
    }
  };

  const int NT = DIM / 64;   // 16
  STAGE(0, 0);
  for (int kt = 0; kt < NT; ++kt) {
    __builtin_amdgcn_s_barrier();                 // A: all waves done reading buf being overwritten
    asm volatile("" ::: "memory");
    if (kt + 1 < NT) STAGE((kt + 1) * 64, (kt + 1) & 1);
    if (kt + 1 < NT) { asm volatile("s_waitcnt vmcnt(8)" ::: "memory"); }
    else             { asm volatile("s_waitcnt vmcnt(0)" ::: "memory"); }
    __builtin_amdgcn_s_barrier();                 // B: buf[kt] visible to all waves
    asm volatile("" ::: "memory");
    COMPUTE(kt & 1);
  }

  // ---- epilogue: up -> bf16 LDS exchange, fuse silu(g)*u, store bf16 h ----
  __syncthreads();   // staging reads done in all waves before smem reuse
  if (mat) {
    u16* ex = smem + sw * (128 * 72);
    #pragma unroll
    for (int fm = 0; fm < 8; ++fm)
      #pragma unroll
      for (int fn = 0; fn < 4; ++fn)
        #pragma unroll
        for (int j = 0; j < 4; ++j)
          ex[(fm * 16 + kgrp * 4 + j) * 72 + fn * 16 + lr] = f2bf(acc[fm][fn][j]);
  }
  __syncthreads();
  if (!mat) {
    const u16* ex = smem + sw * (128 * 72);
    #pragma unroll
    for (int fm = 0; fm < 8; ++fm)
      #pragma unroll
      for (int fn = 0; fn < 4; ++fn) {
        const int col = ct * 128 + wc * 64 + fn * 16 + lr;
        #pragma unroll
        for (int j = 0; j < 4; ++j) {
          const int r = wr * 128 + fm * 16 + kgrp * 4 + j;
          if (row0 + r < cnt) {
            const float gv = acc[fm][fn][j];
            const float uv = bf2f(ex[(fm * 16 + kgrp * 4 + j) * 72 + fn * 16 + lr]);
            const float hv = (gv / (1.f + __expf(-gv))) * uv;
            hbuf[(size_t)(off + row0 + r) * HID + col] = f2bf(hv);
          }
        }
      }
  }
}

// ---------------- GEMM2: out = h @ w2^T, 4 waves, 3-buf pipeline, swizzled LDS (R12/R14 proven) ----------------
__global__ __launch_bounds__(256, 4) void gemm2_bf16(
    const u16* __restrict__ hbuf, const int* __restrict__ cnts,
    const u16* __restrict__ w2b, float* __restrict__ out)
{
  int e, row0, cnt; long long off;
  if (!find_tile(cnts, blockIdx.y, BM, e, row0, cnt, off)) return;
  const int ct = blockIdx.x;

  __shared__ __align__(16) u16 stage[3 * 2 * 4096];   // 48 KB -> 3 blocks/CU

  const int t    = threadIdx.x;
  const int lane = t & 63;
  const int wid  = t >> 6;
  const int wr = wid >> 1, wc = wid & 1;
  const int lr = lane & 15;
  const int lk = (((lane >> 4) ^ ((lr >> 1) & 3)) << 3);

  const u16* arow = hbuf + (size_t)(off + row0) * HID;   // stale rows beyond cnt are finite
  const u16* w2t  = w2b + ((size_t)e * DIM + (size_t)ct * BN) * HID;

  f32x4 acc[4][4];
  const f32x4 zf = {0.f, 0.f, 0.f, 0.f};
  #pragma unroll
  for (int i = 0; i < 4; ++i)
    #pragma unroll
    for (int j = 0; j < 4; ++j) acc[i][j] = zf;

  const int q  = lane >> 2;
  const int cf = (lane & 3) ^ ((q >> 1) & 3);

  auto STAGE = [&](int k0, int b) {
    u16* base = stage + b * (2 * 4096);
    #pragma unroll
    for (int c = 0; c < 2; ++c) {
      const int chunk = wid * 2 + c;
      const int r = chunk * 16 + q;
      const size_t go = (size_t)r * HID + k0 + cf * 8;
      gload16(&arow[go], base        + chunk * 512);
      gload16(&w2t [go], base + 4096 + chunk * 512);
    }
  };
  auto COMPUTE = [&](int b) {
    const u16* Asb = stage + b * (2 * 4096);
    const u16* Bsb = Asb + 4096;
    s16x8 af[4], bf[4];
    #pragma unroll
    for (int fm = 0; fm < 4; ++fm)
      af[fm] = *(const s16x8*)&Asb[(wr * 64 + fm * 16 + lr) * BK + lk];
    #pragma unroll
    for (int fn = 0; fn < 4; ++fn)
      bf[fn] = *(const s16x8*)&Bsb[(wc * 64 + fn * 16 + lr) * BK + lk];
    #pragma unroll
    for (int fm = 0; fm < 4; ++fm)
      #pragma unroll
      for (int fn = 0; fn < 4; ++fn)
        acc[fm][fn] = __builtin_amdgcn_mfma_f32_16x16x32_bf16(af[fm], bf[fn], acc[fm][fn], 0, 0, 0);
  };

  const int NT = HID / BK;   // 64
  STAGE(0, 0);
  STAGE(BK, 1);
  for (int kt = 0; kt < NT; ++kt) {
    if (kt == NT - 1) { asm volatile("s_waitcnt vmcnt(0)" ::: "memory"); }
    else              { asm volatile("s_waitcnt vmcnt(4)" ::: "memory"); }
    __builtin_amdgcn_s_barrier();
    asm volatile("" ::: "memory");
    if (kt + 2 < NT) STAGE((kt + 2) * BK, (kt + 2) % 3);
    COMPUTE(kt % 3);
  }

  #pragma unroll
  for (int fm = 0; fm < 4; ++fm)
    #pragma unroll
    for (int fn = 0; fn < 4; ++fn) {
      const int col = ct * BN + wc * 64 + fn * 16 + lr;
      #pragma unroll
      for (int j = 0; j < 4; ++j) {
        const int r = wr * 64 + fm * 16 + ((lane >> 4) << 2) + j;
        if (row0 + r < cnt)
          out[(size_t)(off + row0 + r) * DIM + col] = acc[fm][fn][j];
      }
    }
}

// ---------------- fallback path (round-2, in-kernel cvt) ----------------
__global__ __launch_bounds__(256) void gemm1_kernel(
    const float* __restrict__ x, const int* __restrict__ cnts,
    const float* __restrict__ w1, const float* __restrict__ w3,
    u16* __restrict__ hbuf)
{
  int e, row0, cnt; long long off;
  if (!find_tile(cnts, blockIdx.y, BM, e, row0, cnt, off)) return;
  const int ct = blockIdx.x;

  __shared__ u16 As [BM * LDK];
  __shared__ u16 B1s[BN * LDK];
  __shared__ u16 B3s[BN * LDK];

  const int t    = threadIdx.x;
  const int srow = t >> 3;
  const int skq  = (t & 7) * 4;
  const int lane = t & 63;
  const int wid  = t >> 6;
  const int wr = wid >> 1, wc = wid & 1;
  const int lr = lane & 15;
  const int lk = (lane >> 4) * 8;

  const float* w1e = w1 + (size_t)e * HID * DIM;
  const float* w3e = w3 + (size_t)e * HID * DIM;

  f32x4 accg[4][4], accu[4][4];
  const f32x4 zf = {0.f, 0.f, 0.f, 0.f};
  #pragma unroll
  for (int i = 0; i < 4; ++i)
    #pragma unroll
    for (int j = 0; j < 4; ++j) { accg[i][j] = zf; accu[i][j] = zf; }

  for (int k0 = 0; k0 < DIM; k0 += BK) {
    __syncthreads();
    #pragma unroll
    for (int s = 0; s < 4; ++s) {
      const int r = s * 32 + srow;
      float4 va = make_float4(0.f, 0.f, 0.f, 0.f);
      const int gm = row0 + r;
      if (gm < cnt) va = *(const float4*)&x[(size_t)(off + gm) * DIM + k0 + skq];
      ushort4 ua; ua.x = f2bf(va.x); ua.y = f2bf(va.y); ua.z = f2bf(va.z); ua.w = f2bf(va.w);
      *(ushort4*)&As[r * LDK + skq] = ua;
      const size_t gb = (size_t)(ct * BN + r) * DIM + k0 + skq;
      const float4 v1 = *(const float4*)&w1e[gb];
      const float4 v3 = *(const float4*)&w3e[gb];
      ushort4 u1; u1.x = f2bf(v1.x); u1.y = f2bf(v1.y); u1.z = f2bf(v1.z); u1.w = f2bf(v1.w);
      ushort4 u3; u3.x = f2bf(v3.x); u3.y = f2bf(v3.y); u3.z = f2bf(v3.z); u3.w = f2bf(v3.w);
      *(ushort4*)&B1s[r * LDK + skq] = u1;
      *(ushort4*)&B3s[r * LDK + skq] = u3;
    }
    __syncthreads();

    s16x8 af[4], b1f[4], b3f[4];
    #pragma unroll
    for (int fm = 0; fm < 4; ++fm)
      af[fm] = *(const s16x8*)&As[(wr * 64 + fm * 16 + lr) * LDK + lk];
    #pragma unroll
    for (int fn = 0; fn < 4; ++fn) {
      b1f[fn] = *(const s16x8*)&B1s[(wc * 64 + fn * 16 + lr) * LDK + lk];
      b3f[fn] = *(const s16x8*)&B3s[(wc * 64 + fn * 16 + lr) * LDK + lk];
    }
    #pragma unroll
    for (int fm = 0; fm < 4; ++fm)
      #pragma unroll
      for (int fn = 0; fn < 4; ++fn) {
        accg[fm][fn] = __builtin_amdgcn_mfma_f32_16x16x32_bf16(af[fm], b1f[fn], accg[fm][fn], 0, 0, 0);
        accu[fm][fn] = __builtin_amdgcn_mfma_f32_16x16x32_bf16(af[fm], b3f[fn], accu[fm][fn], 0, 0, 0);
      }
  }

  #pragma unroll
  for (int fm = 0; fm < 4; ++fm)
    #pragma unroll
    for (int fn = 0; fn < 4; ++fn) {
      const f32x4 g = accg[fm][fn], u = accu[fm][fn];
      const int col = ct * BN + wc * 64 + fn * 16 + lr;
      #pragma unroll
      for (int j = 0; j < 4; ++j) {
        const int r = wr * 64 + fm * 16 + ((lane >> 4) << 2) + j;
        if (row0 + r < cnt) {
          const float gv = g[j];
          const float hv = (gv / (1.f + __expf(-gv))) * u[j];
          hbuf[(size_t)(off + row0 + r) * HID + col] = f2bf(hv);
        }
      }
    }
}

__global__ __launch_bounds__(256) void gemm2_kernel(
    const u16* __restrict__ hbuf, const int* __restrict__ cnts,
    const float* __restrict__ w2, float* __restrict__ out)
{
  int e, row0, cnt; long long off;
  if (!find_tile(cnts, blockIdx.y, BM, e, row0, cnt, off)) return;
  const int ct = blockIdx.x;

  __shared__ u16 As[BM * LDK];
  __shared__ u16 Bs[BN * LDK];

  const int t    = threadIdx.x;
  const int srow = t >> 3;
  const int skq  = (t & 7) * 4;
  const int lane = t & 63;
  const int wid  = t >> 6;
  const int wr = wid >> 1, wc = wid & 1;
  const int lr = lane & 15;
  const int lk = (lane >> 4) * 8;

  const float* w2e = w2 + (size_t)e * DIM * HID;

  f32x4 acc[4][4];
  const f32x4 zf = {0.f, 0.f, 0.f, 0.f};
  #pragma unroll
  for (int i = 0; i < 4; ++i)
    #pragma unroll
    for (int j = 0; j < 4; ++j) acc[i][j] = zf;

  for (int k0 = 0; k0 < HID; k0 += BK) {
    __syncthreads();
    #pragma unroll
    for (int s = 0; s < 4; ++s) {
      const int r = s * 32 + srow;
      ushort4 ua = make_ushort4(0, 0, 0, 0);
      const int gm = row0 + r;
      if (gm < cnt) ua = *(const ushort4*)&hbuf[(size_t)(off + gm) * HID + k0 + skq];
      *(ushort4*)&As[r * LDK + skq] = ua;
      const float4 v2 = *(const float4*)&w2e[(size_t)(ct * BN + r) * HID + k0 + skq];
      ushort4 u2; u2.x = f2bf(v2.x); u2.y = f2bf(v2.y); u2.z = f2bf(v2.z); u2.w = f2bf(v2.w);
      *(ushort4*)&Bs[r * LDK + skq] = u2;
    }
    __syncthreads();

    s16x8 af[4], bf[4];
    #pragma unroll
    for (int fm = 0; fm < 4; ++fm)
      af[fm] = *(const s16x8*)&As[(wr * 64 + fm * 16 + lr) * LDK + lk];
    #pragma unroll
    for (int fn = 0; fn < 4; ++fn)
      bf[fn] = *(const s16x8*)&Bs[(wc * 64 + fn * 16 + lr) * LDK + lk];
    #pragma unroll
    for (int fm = 0; fm < 4; ++fm)
      #pragma unroll
      for (int fn = 0; fn < 4; ++fn)
        acc[fm][fn] = __builtin_amdgcn_mfma_f32_16x16x32_bf16(af[fm], bf[fn], acc[fm][fn], 0, 0, 0);
  }

  #pragma unroll
  for (int fm = 0; fm < 4; ++fm)
    #pragma unroll
    for (int fn = 0; fn < 4; ++fn) {
      const int col = ct * BN + wc * 64 + fn * 16 + lr;
      #pragma unroll
      for (int j = 0; j < 4; ++j) {
        const int r = wr * 64 + fm * 16 + ((lane >> 4) << 2) + j;
        if (row0 + r < cnt)
          out[(size_t)(off + row0 + r) * DIM + col] = acc[fm][fn][j];
      }
    }
}

// Zero padding rows [total, NTOK) — grid-stride (222 rows of real work).
__global__ void zero_pad_kernel(const int* __restrict__ cnts, float* __restrict__ out)
{
  int total = 0;
  #pragma unroll
  for (int e = 0; e < NEXP; ++e) total += cnts[e];
  for (int row = total + blockIdx.x; row < NTOK; row += gridDim.x) {
    float4* p = (float4*)(out + (size_t)row * DIM);
    p[threadIdx.x] = make_float4(0.f, 0.f, 0.f, 0.f);
  }
}

extern "C" void kernel_launch(void* const* d_in, const int* in_sizes, int n_in,
                              void* d_out, int out_size, void* d_ws, size_t ws_size,
                              hipStream_t stream) {
  const float* x    = (const float*)d_in[0];
  const int*   cnts = (const int*)d_in[1];
  const float* w1   = (const float*)d_in[2];
  const float* w2   = (const float*)d_in[3];
  const float* w3   = (const float*)d_in[4];
  float*       out  = (float*)d_out;

  const size_t HBUF_E = (size_t)NTOK * HID;        // 16.78M
  const size_t XB_E   = (size_t)NTOK * DIM;        //  8.39M
  const size_t W_E    = (size_t)NEXP * HID * DIM;  // 16.78M
  const size_t need_min  = (HBUF_E + XB_E + 2 * W_E) * sizeof(u16);   // 112 MB
  const size_t need_full = (HBUF_E + XB_E + 3 * W_E) * sizeof(u16);   // 151 MB

  u16* hbuf = (u16*)d_ws;
  dim3 blk(256);
  const int XB32 = (int)(XB_E / 32), W32 = (int)(W_E / 32);
  const int W4   = (int)(W_E / 4);

  if (ws_size >= need_full) {
    u16* xb = hbuf + HBUF_E;
    u16* wA = xb + XB_E;     // w1
    u16* wB = wA + W_E;      // w3
    u16* wC = wB + W_E;      // w2 (converted by gemm1's tail-rider blocks)
    cvt_multi<<<dim3(2048), blk, 0, stream>>>(x, xb, XB32, w1, wA, W32, w3, wB, W32,
                                              (const float*)nullptr, (u16*)nullptr, 0);
    gemm1_bf16<<<dim3(HID / 128, G1Y + CVTY), dim3(512), 0, stream>>>(xb, cnts, wA, wB, hbuf, w2, wC, W4);
    gemm2_bf16<<<dim3(DIM / BN, 72), blk, 0, stream>>>(hbuf, cnts, wC, out);
  } else if (ws_size >= need_min) {
    u16* xb = hbuf + HBUF_E;
    u16* wA = xb + XB_E;     // w1, then reused for w2
    u16* wB = wA + W_E;      // w3
    cvt_multi<<<dim3(2048), blk, 0, stream>>>(x, xb, XB32, w1, wA, W32, w3, wB, W32,
                                              (const float*)nullptr, (u16*)nullptr, 0);
    gemm1_bf16<<<dim3(HID / 128, G1Y + CVTY), dim3(512), 0, stream>>>(xb, cnts, wA, wB, hbuf,
                                                                      (const float*)nullptr, (u16*)nullptr, 0);
    cvt_multi<<<dim3(2048), blk, 0, stream>>>(w2, wA, W32, (const float*)nullptr, (u16*)nullptr, 0,
                                              (const float*)nullptr, (u16*)nullptr, 0,
                                              (const float*)nullptr, (u16*)nullptr, 0);
    gemm2_bf16<<<dim3(DIM / BN, 72), blk, 0, stream>>>(hbuf, cnts, wA, out);
  } else {
    gemm1_kernel<<<dim3(HID / BN, 72), blk, 0, stream>>>(x, cnts, w1, w3, hbuf);
    gemm2_kernel<<<dim3(DIM / BN, 72), blk, 0, stream>>>(hbuf, cnts, w2, out);
  }
  zero_pad_kernel<<<dim3(64), dim3(256), 0, stream>>>(cnts, out);
}

// Round 16
// 197.234 us; speedup vs baseline: 1.0784x; 1.0784x over previous
//
#include <hip/hip_runtime.h>

#define NEXP 8
#define DIM  1024
#define HID  2048
#define NTOK 8192

#define BM 128
#define BN 128
#define BK 32
#define LDK 40    // fallback path: padded LDS stride
#define GY 72     // gemm1 grid: y-rows [0,72) are GEMM tiles; [72, 72+CVTY) are w2-cvt riders (tail-fill)
#define CVTY 16

typedef short s16x8 __attribute__((ext_vector_type(8)));
typedef float f32x4 __attribute__((ext_vector_type(4)));
typedef unsigned short u16;

__device__ __forceinline__ u16 f2bf(float f) {
  unsigned int u = __builtin_bit_cast(unsigned int, f);
  u += 0x7FFFu + ((u >> 16) & 1u);   // RNE
  return (u16)(u >> 16);
}

__device__ __forceinline__ ushort4 cvt4(float4 a) {
  ushort4 r; r.x = f2bf(a.x); r.y = f2bf(a.y); r.z = f2bf(a.z); r.w = f2bf(a.w); return r;
}

// async global->LDS, 16B per lane; LDS dest must be wave-uniform base (HW adds lane*16)
__device__ __forceinline__ void gload16(const u16* g, u16* l) {
  __builtin_amdgcn_global_load_lds((const __attribute__((address_space(1))) void*)g,
                                   (__attribute__((address_space(3))) void*)l, 16, 0, 0);
}

// Flat row-tile scheduler over the 8 experts. Max total row tiles = 64 + 7 < 72.
// Harness passes integer inputs as int32.
__device__ __forceinline__ bool find_tile(const int* __restrict__ cnts, int rt,
                                          int& e_out, int& row0, int& cnt_out, long long& off_out) {
  long long off = 0; int cum = 0;
  #pragma unroll
  for (int e = 0; e < NEXP; ++e) {
    int c = cnts[e];
    int nt = (c + BM - 1) / BM;
    if (rt < cum + nt) { e_out = e; row0 = (rt - cum) * BM; cnt_out = c; off_out = off; return true; }
    cum += nt; off += c;
  }
  return false;
}

// ---------------- fp32 -> bf16 conversion: combined flat index, 32-float units ----------------
// R6-measured best pattern: 3.74 TB/s moved bytes.
__device__ __forceinline__ void cvt32(const float* __restrict__ s, u16* __restrict__ d, int j) {
  const float4* p = (const float4*)s + 8 * (size_t)j;
  float4 a[8];
  #pragma unroll
  for (int q = 0; q < 8; ++q) a[q] = p[q];   // 8 independent 16B loads in flight
  s16x8* dst = (s16x8*)d + 4 * (size_t)j;
  #pragma unroll
  for (int q = 0; q < 4; ++q) {
    s16x8 v;
    v[0] = (short)f2bf(a[2*q].x);   v[1] = (short)f2bf(a[2*q].y);
    v[2] = (short)f2bf(a[2*q].z);   v[3] = (short)f2bf(a[2*q].w);
    v[4] = (short)f2bf(a[2*q+1].x); v[5] = (short)f2bf(a[2*q+1].y);
    v[6] = (short)f2bf(a[2*q+1].z); v[7] = (short)f2bf(a[2*q+1].w);
    dst[q] = v;
  }
}

// n* in units of 32 floats
__global__ __launch_bounds__(256) void cvt_multi(
    const float* __restrict__ s0, u16* __restrict__ d0, int n0,
    const float* __restrict__ s1, u16* __restrict__ d1, int n1,
    const float* __restrict__ s2, u16* __restrict__ d2, int n2,
    const float* __restrict__ s3, u16* __restrict__ d3, int n3) {
  const int b0 = n0, b1 = b0 + n1, b2 = b1 + n2, b3 = b2 + n3;
  for (int i = blockIdx.x * blockDim.x + threadIdx.x; i < b3; i += gridDim.x * blockDim.x) {
    if      (i < b0) cvt32(s0, d0, i);
    else if (i < b1) cvt32(s1, d1, i - b0);
    else if (i < b2) cvt32(s2, d2, i - b1);
    else             cvt32(s3, d3, i - b2);
  }
}

// ---------------- GEMM1: 8 waves, matmul split across waves, 3-buf pipeline, swizzled LDS ----------------
// waves 0-3: gate = x@w1^T; waves 4-7: up = x@w3^T (same output subtiles).
// LDS swizzle (verified R8: bank conflicts 8.4M -> 0): linear gload_lds dest +
// inverse-swizzled GLOBAL source colblk + same-XOR read offset.
// y-rows >= GY are w2-cvt riders: dispatched LAST -> they backfill the dispatch-tail holes.
#define XSTR 68   // f32 LDS stride for up-exchange (2-way bank aliasing only)
__global__ __launch_bounds__(512, 4) void gemm1_bf16(
    const u16* __restrict__ xb, const int* __restrict__ cnts,
    const u16* __restrict__ w1b, const u16* __restrict__ w3b,
    u16* __restrict__ hbuf,
    const float* __restrict__ w2f, u16* __restrict__ wC, int nW4)
{
  if (blockIdx.y >= GY) {
    // w2 conversion rider blocks (dispatched after all GEMM tiles; fill dispatch-tail idle slots)
    if (nW4) {
      const int cb = (blockIdx.y - GY) * gridDim.x + blockIdx.x;
      const int T  = CVTY * gridDim.x * 512;
      int i = cb * 512 + threadIdx.x;
      const float4* __restrict__ src = (const float4*)w2f;
      ushort4* __restrict__ dst = (ushort4*)wC;
      for (; i + 3 * T < nW4; i += 4 * T) {
        const float4 a0 = src[i];
        const float4 a1 = src[i + T];
        const float4 a2 = src[i + 2 * T];
        const float4 a3 = src[i + 3 * T];
        dst[i]         = cvt4(a0);
        dst[i + T]     = cvt4(a1);
        dst[i + 2 * T] = cvt4(a2);
        dst[i + 3 * T] = cvt4(a3);
      }
      for (; i < nW4; i += T) dst[i] = cvt4(src[i]);
    }
    return;
  }

  int e, row0, cnt; long long off;
  if (!find_tile(cnts, blockIdx.y, e, row0, cnt, off)) return;
  const int ct = blockIdx.x;

  // union: 3 staging bufs (3 * 3 tiles * 8KB = 72KB) in loop; up-exchange (69.6KB f32) in epilogue
  __shared__ __align__(16) u16 smem[3 * 3 * 4096];   // 73728 B -> 2 blocks/CU
  u16* stage = smem;
  float* smem_f = (float*)smem;

  const int t    = threadIdx.x;
  const int lane = t & 63;
  const int wid  = t >> 6;          // 0..7
  const int mat  = wid >> 2;        // 0 = gate/w1, 1 = up/w3
  const int sw   = wid & 3;         // output subtile id
  const int wr = sw >> 1, wc = sw & 1;
  const int lr = lane & 15;
  const int lk = (((lane >> 4) ^ ((lr >> 1) & 3)) << 3);   // swizzled fragment-read offset

  const u16* xrow = xb + (size_t)(off + row0) * DIM;   // overreads stay inside x alloc
  const u16* w1t  = w1b + ((size_t)e * HID + (size_t)ct * BN) * DIM;
  const u16* w3t  = w3b + ((size_t)e * HID + (size_t)ct * BN) * DIM;

  f32x4 acc[4][4];
  const f32x4 zf = {0.f, 0.f, 0.f, 0.f};
  #pragma unroll
  for (int i = 0; i < 4; ++i)
    #pragma unroll
    for (int j = 0; j < 4; ++j) acc[i][j] = zf;

  // staging geometry: dest chunk (srow, cs=lane&3) gets global colblk cf
  const int q    = lane >> 2;                 // 0..15
  const int cf   = (lane & 3) ^ ((q >> 1) & 3);
  const int srow = wid * 16 + q;
  const int scol = cf * 8;

  auto STAGE = [&](int k0, int b) {     // 3 gload_lds per wave
    u16* base = stage + b * (3 * 4096);
    const size_t go = (size_t)srow * DIM + k0 + scol;
    gload16(&xrow[go], base        + wid * 512);
    gload16(&w1t [go], base + 4096 + wid * 512);
    gload16(&w3t [go], base + 8192 + wid * 512);
  };
  auto COMPUTE = [&](int b) {
    const u16* Asb = stage + b * (3 * 4096);
    const u16* Bsb = Asb + 4096 + mat * 4096;         // wave-uniform w1/w3 select
    s16x8 af[4], bf[4];
    #pragma unroll
    for (int fm = 0; fm < 4; ++fm)
      af[fm] = *(const s16x8*)&Asb[(wr * 64 + fm * 16 + lr) * BK + lk];
    #pragma unroll
    for (int fn = 0; fn < 4; ++fn)
      bf[fn] = *(const s16x8*)&Bsb[(wc * 64 + fn * 16 + lr) * BK + lk];
    // no s_setprio: m190 evidence it hurts lockstep barrier-synced GEMM
    #pragma unroll
    for (int fm = 0; fm < 4; ++fm)
      #pragma unroll
      for (int fn = 0; fn < 4; ++fn)
        acc[fm][fn] = __builtin_amdgcn_mfma_f32_16x16x32_bf16(af[fm], bf[fn], acc[fm][fn], 0, 0, 0);
  };

  const int NT = DIM / BK;   // 32
  STAGE(0, 0);
  STAGE(BK, 1);
  for (int kt = 0; kt < NT; ++kt) {
    if (kt == NT - 1) { asm volatile("s_waitcnt vmcnt(0)" ::: "memory"); }
    else              { asm volatile("s_waitcnt vmcnt(3)" ::: "memory"); }
    __builtin_amdgcn_s_barrier();
    asm volatile("" ::: "memory");          // keep LDS reads below the barrier
    if (kt + 2 < NT) STAGE((kt + 2) * BK, (kt + 2) % 3);
    COMPUTE(kt % 3);
  }

  // ---- epilogue: exchange up via LDS, fuse silu(g)*u, store bf16 h ----
  __syncthreads();   // last COMPUTE's LDS reads done in all waves before smem reuse
  if (mat) {
    float* up = smem_f + sw * (64 * XSTR);
    #pragma unroll
    for (int fm = 0; fm < 4; ++fm)
      #pragma unroll
      for (int fn = 0; fn < 4; ++fn)
        #pragma unroll
        for (int j = 0; j < 4; ++j)
          up[(fm * 16 + ((lane >> 4) << 2) + j) * XSTR + fn * 16 + lr] = acc[fm][fn][j];
  }
  __syncthreads();
  if (!mat) {
    const float* up = smem_f + sw * (64 * XSTR);
    #pragma unroll
    for (int fm = 0; fm < 4; ++fm)
      #pragma unroll
      for (int fn = 0; fn < 4; ++fn) {
        const int col = ct * BN + wc * 64 + fn * 16 + lr;
        #pragma unroll
        for (int j = 0; j < 4; ++j) {
          const int r = wr * 64 + fm * 16 + ((lane >> 4) << 2) + j;
          if (row0 + r < cnt) {
            const float gv = acc[fm][fn][j];
            const float uv = up[(fm * 16 + ((lane >> 4) << 2) + j) * XSTR + fn * 16 + lr];
            const float hv = (gv / (1.f + __expf(-gv))) * uv;
            hbuf[(size_t)(off + row0 + r) * HID + col] = f2bf(hv);
          }
        }
      }
  }
}

// ---------------- GEMM2: out = h @ w2^T, 4 waves, 3-buf pipeline, swizzled LDS (915 TF) ----------------
__global__ __launch_bounds__(256, 4) void gemm2_bf16(
    const u16* __restrict__ hbuf, const int* __restrict__ cnts,
    const u16* __restrict__ w2b, float* __restrict__ out)
{
  int e, row0, cnt; long long off;
  if (!find_tile(cnts, blockIdx.y, e, row0, cnt, off)) return;
  const int ct = blockIdx.x;

  __shared__ __align__(16) u16 stage[3 * 2 * 4096];   // 48 KB -> 3 blocks/CU

  const int t    = threadIdx.x;
  const int lane = t & 63;
  const int wid  = t >> 6;
  const int wr = wid >> 1, wc = wid & 1;
  const int lr = lane & 15;
  const int lk = (((lane >> 4) ^ ((lr >> 1) & 3)) << 3);

  const u16* arow = hbuf + (size_t)(off + row0) * HID;   // stale rows beyond cnt are finite
  const u16* w2t  = w2b + ((size_t)e * DIM + (size_t)ct * BN) * HID;

  f32x4 acc[4][4];
  const f32x4 zf = {0.f, 0.f, 0.f, 0.f};
  #pragma unroll
  for (int i = 0; i < 4; ++i)
    #pragma unroll
    for (int j = 0; j < 4; ++j) acc[i][j] = zf;

  const int q  = lane >> 2;
  const int cf = (lane & 3) ^ ((q >> 1) & 3);

  auto STAGE = [&](int k0, int b) {     // 4 gload_lds per wave
    u16* base = stage + b * (2 * 4096);
    #pragma unroll
    for (int c = 0; c < 2; ++c) {
      const int chunk = wid * 2 + c;
      const int r = chunk * 16 + q;
      const size_t go = (size_t)r * HID + k0 + cf * 8;
      gload16(&arow[go], base        + chunk * 512);
      gload16(&w2t [go], base + 4096 + chunk * 512);
    }
  };
  auto COMPUTE = [&](int b) {
    const u16* Asb = stage + b * (2 * 4096);
    const u16* Bsb = Asb + 4096;
    s16x8 af[4], bf[4];
    #pragma unroll
    for (int fm = 0; fm < 4; ++fm)
      af[fm] = *(const s16x8*)&Asb[(wr * 64 + fm * 16 + lr) * BK + lk];
    #pragma unroll
    for (int fn = 0; fn < 4; ++fn)
      bf[fn] = *(const s16x8*)&Bsb[(wc * 64 + fn * 16 + lr) * BK + lk];
    #pragma unroll
    for (int fm = 0; fm < 4; ++fm)
      #pragma unroll
      for (int fn = 0; fn < 4; ++fn)
        acc[fm][fn] = __builtin_amdgcn_mfma_f32_16x16x32_bf16(af[fm], bf[fn], acc[fm][fn], 0, 0, 0);
  };

  const int NT = HID / BK;   // 64
  STAGE(0, 0);
  STAGE(BK, 1);
  for (int kt = 0; kt < NT; ++kt) {
    if (kt == NT - 1) { asm volatile("s_waitcnt vmcnt(0)" ::: "memory"); }
    else              { asm volatile("s_waitcnt vmcnt(4)" ::: "memory"); }
    __builtin_amdgcn_s_barrier();
    asm volatile("" ::: "memory");
    if (kt + 2 < NT) STAGE((kt + 2) * BK, (kt + 2) % 3);
    COMPUTE(kt % 3);
  }

  #pragma unroll
  for (int fm = 0; fm < 4; ++fm)
    #pragma unroll
    for (int fn = 0; fn < 4; ++fn) {
      const int col = ct * BN + wc * 64 + fn * 16 + lr;
      #pragma unroll
      for (int j = 0; j < 4; ++j) {
        const int r = wr * 64 + fm * 16 + ((lane >> 4) << 2) + j;
        if (row0 + r < cnt)
          out[(size_t)(off + row0 + r) * DIM + col] = acc[fm][fn][j];
      }
    }
}

// ---------------- fallback path (round-2, in-kernel cvt) ----------------
__global__ __launch_bounds__(256) void gemm1_kernel(
    const float* __restrict__ x, const int* __restrict__ cnts,
    const float* __restrict__ w1, const float* __restrict__ w3,
    u16* __restrict__ hbuf)
{
  int e, row0, cnt; long long off;
  if (!find_tile(cnts, blockIdx.y, e, row0, cnt, off)) return;
  const int ct = blockIdx.x;

  __shared__ u16 As [BM * LDK];
  __shared__ u16 B1s[BN * LDK];
  __shared__ u16 B3s[BN * LDK];

  const int t    = threadIdx.x;
  const int srow = t >> 3;
  const int skq  = (t & 7) * 4;
  const int lane = t & 63;
  const int wid  = t >> 6;
  const int wr = wid >> 1, wc = wid & 1;
  const int lr = lane & 15;
  const int lk = (lane >> 4) * 8;

  const float* w1e = w1 + (size_t)e * HID * DIM;
  const float* w3e = w3 + (size_t)e * HID * DIM;

  f32x4 accg[4][4], accu[4][4];
  const f32x4 zf = {0.f, 0.f, 0.f, 0.f};
  #pragma unroll
  for (int i = 0; i < 4; ++i)
    #pragma unroll
    for (int j = 0; j < 4; ++j) { accg[i][j] = zf; accu[i][j] = zf; }

  for (int k0 = 0; k0 < DIM; k0 += BK) {
    __syncthreads();
    #pragma unroll
    for (int s = 0; s < 4; ++s) {
      const int r = s * 32 + srow;
      float4 va = make_float4(0.f, 0.f, 0.f, 0.f);
      const int gm = row0 + r;
      if (gm < cnt) va = *(const float4*)&x[(size_t)(off + gm) * DIM + k0 + skq];
      ushort4 ua; ua.x = f2bf(va.x); ua.y = f2bf(va.y); ua.z = f2bf(va.z); ua.w = f2bf(va.w);
      *(ushort4*)&As[r * LDK + skq] = ua;
      const size_t gb = (size_t)(ct * BN + r) * DIM + k0 + skq;
      const float4 v1 = *(const float4*)&w1e[gb];
      const float4 v3 = *(const float4*)&w3e[gb];
      ushort4 u1; u1.x = f2bf(v1.x); u1.y = f2bf(v1.y); u1.z = f2bf(v1.z); u1.w = f2bf(v1.w);
      ushort4 u3; u3.x = f2bf(v3.x); u3.y = f2bf(v3.y); u3.z = f2bf(v3.z); u3.w = f2bf(v3.w);
      *(ushort4*)&B1s[r * LDK + skq] = u1;
      *(ushort4*)&B3s[r * LDK + skq] = u3;
    }
    __syncthreads();

    s16x8 af[4], b1f[4], b3f[4];
    #pragma unroll
    for (int fm = 0; fm < 4; ++fm)
      af[fm] = *(const s16x8*)&As[(wr * 64 + fm * 16 + lr) * LDK + lk];
    #pragma unroll
    for (int fn = 0; fn < 4; ++fn) {
      b1f[fn] = *(const s16x8*)&B1s[(wc * 64 + fn * 16 + lr) * LDK + lk];
      b3f[fn] = *(const s16x8*)&B3s[(wc * 64 + fn * 16 + lr) * LDK + lk];
    }
    #pragma unroll
    for (int fm = 0; fm < 4; ++fm)
      #pragma unroll
      for (int fn = 0; fn < 4; ++fn) {
        accg[fm][fn] = __builtin_amdgcn_mfma_f32_16x16x32_bf16(af[fm], b1f[fn], accg[fm][fn], 0, 0, 0);
        accu[fm][fn] = __builtin_amdgcn_mfma_f32_16x16x32_bf16(af[fm], b3f[fn], accu[fm][fn], 0, 0, 0);
      }
  }

  #pragma unroll
  for (int fm = 0; fm < 4; ++fm)
    #pragma unroll
    for (int fn = 0; fn < 4; ++fn) {
      const f32x4 g = accg[fm][fn], u = accu[fm][fn];
      const int col = ct * BN + wc * 64 + fn * 16 + lr;
      #pragma unroll
      for (int j = 0; j < 4; ++j) {
        const int r = wr * 64 + fm * 16 + ((lane >> 4) << 2) + j;
        if (row0 + r < cnt) {
          const float gv = g[j];
          const float hv = (gv / (1.f + __expf(-gv))) * u[j];
          hbuf[(size_t)(off + row0 + r) * HID + col] = f2bf(hv);
        }
      }
    }
}

__global__ __launch_bounds__(256) void gemm2_kernel(
    const u16* __restrict__ hbuf, const int* __restrict__ cnts,
    const float* __restrict__ w2, float* __restrict__ out)
{
  int e, row0, cnt; long long off;
  if (!find_tile(cnts, blockIdx.y, e, row0, cnt, off)) return;
  const int ct = blockIdx.x;

  __shared__ u16 As[BM * LDK];
  __shared__ u16 Bs[BN * LDK];

  const int t    = threadIdx.x;
  const int srow = t >> 3;
  const int skq  = (t & 7) * 4;
  const int lane = t & 63;
  const int wid  = t >> 6;
  const int wr = wid >> 1, wc = wid & 1;
  const int lr = lane & 15;
  const int lk = (lane >> 4) * 8;

  const float* w2e = w2 + (size_t)e * DIM * HID;

  f32x4 acc[4][4];
  const f32x4 zf = {0.f, 0.f, 0.f, 0.f};
  #pragma unroll
  for (int i = 0; i < 4; ++i)
    #pragma unroll
    for (int j = 0; j < 4; ++j) acc[i][j] = zf;

  for (int k0 = 0; k0 < HID; k0 += BK) {
    __syncthreads();
    #pragma unroll
    for (int s = 0; s < 4; ++s) {
      const int r = s * 32 + srow;
      ushort4 ua = make_ushort4(0, 0, 0, 0);
      const int gm = row0 + r;
      if (gm < cnt) ua = *(const ushort4*)&hbuf[(size_t)(off + gm) * HID + k0 + skq];
      *(ushort4*)&As[r * LDK + skq] = ua;
      const float4 v2 = *(const float4*)&w2e[(size_t)(ct * BN + r) * HID + k0 + skq];
      ushort4 u2; u2.x = f2bf(v2.x); u2.y = f2bf(v2.y); u2.z = f2bf(v2.z); u2.w = f2bf(v2.w);
      *(ushort4*)&Bs[r * LDK + skq] = u2;
    }
    __syncthreads();

    s16x8 af[4], bf[4];
    #pragma unroll
    for (int fm = 0; fm < 4; ++fm)
      af[fm] = *(const s16x8*)&As[(wr * 64 + fm * 16 + lr) * LDK + lk];
    #pragma unroll
    for (int fn = 0; fn < 4; ++fn)
      bf[fn] = *(const s16x8*)&Bs[(wc * 64 + fn * 16 + lr) * LDK + lk];
    #pragma unroll
    for (int fm = 0; fm < 4; ++fm)
      #pragma unroll
      for (int fn = 0; fn < 4; ++fn)
        acc[fm][fn] = __builtin_amdgcn_mfma_f32_16x16x32_bf16(af[fm], bf[fn], acc[fm][fn], 0, 0, 0);
  }

  #pragma unroll
  for (int fm = 0; fm < 4; ++fm)
    #pragma unroll
    for (int fn = 0; fn < 4; ++fn) {
      const int col = ct * BN + wc * 64 + fn * 16 + lr;
      #pragma unroll
      for (int j = 0; j < 4; ++j) {
        const int r = wr * 64 + fm * 16 + ((lane >> 4) << 2) + j;
        if (row0 + r < cnt)
          out[(size_t)(off + row0 + r) * DIM + col] = acc[fm][fn][j];
      }
    }
}

// Zero padding rows [total, NTOK) — grid-stride (222 rows of real work).
__global__ void zero_pad_kernel(const int* __restrict__ cnts, float* __restrict__ out)
{
  int total = 0;
  #pragma unroll
  for (int e = 0; e < NEXP; ++e) total += cnts[e];
  for (int row = total + blockIdx.x; row < NTOK; row += gridDim.x) {
    float4* p = (float4*)(out + (size_t)row * DIM);
    p[threadIdx.x] = make_float4(0.f, 0.f, 0.f, 0.f);
  }
}

extern "C" void kernel_launch(void* const* d_in, const int* in_sizes, int n_in,
                              void* d_out, int out_size, void* d_ws, size_t ws_size,
                              hipStream_t stream) {
  const float* x    = (const float*)d_in[0];
  const int*   cnts = (const int*)d_in[1];
  const float* w1   = (const float*)d_in[2];
  const float* w2   = (const float*)d_in[3];
  const float* w3   = (const float*)d_in[4];
  float*       out  = (float*)d_out;

  const size_t HBUF_E = (size_t)NTOK * HID;        // 16.78M
  const size_t XB_E   = (size_t)NTOK * DIM;        //  8.39M
  const size_t W_E    = (size_t)NEXP * HID * DIM;  // 16.78M
  const size_t need_min  = (HBUF_E + XB_E + 2 * W_E) * sizeof(u16);   // 112 MB
  const size_t need_full = (HBUF_E + XB_E + 3 * W_E) * sizeof(u16);   // 151 MB

  u16* hbuf = (u16*)d_ws;
  dim3 blk(256);
  const int XB32 = (int)(XB_E / 32), W32 = (int)(W_E / 32);
  const int W4   = (int)(W_E / 4);

  if (ws_size >= need_full) {
    u16* xb = hbuf + HBUF_E;
    u16* wA = xb + XB_E;     // w1
    u16* wB = wA + W_E;      // w3
    u16* wC = wB + W_E;      // w2 (converted by gemm1's tail-rider blocks)
    cvt_multi<<<dim3(2048), blk, 0, stream>>>(x, xb, XB32, w1, wA, W32, w3, wB, W32,
                                              (const float*)nullptr, (u16*)nullptr, 0);
    gemm1_bf16<<<dim3(HID / BN, GY + CVTY), dim3(512), 0, stream>>>(xb, cnts, wA, wB, hbuf, w2, wC, W4);
    gemm2_bf16<<<dim3(DIM / BN, 72), blk, 0, stream>>>(hbuf, cnts, wC, out);
  } else if (ws_size >= need_min) {
    u16* xb = hbuf + HBUF_E;
    u16* wA = xb + XB_E;     // w1, then reused for w2
    u16* wB = wA + W_E;      // w3
    cvt_multi<<<dim3(2048), blk, 0, stream>>>(x, xb, XB32, w1, wA, W32, w3, wB, W32,
                                              (const float*)nullptr, (u16*)nullptr, 0);
    gemm1_bf16<<<dim3(HID / BN, GY + CVTY), dim3(512), 0, stream>>>(xb, cnts, wA, wB, hbuf,
                                                                    (const float*)nullptr, (u16*)nullptr, 0);
    cvt_multi<<<dim3(2048), blk, 0, stream>>>(w2, wA, W32, (const float*)nullptr, (u16*)nullptr, 0,
                                              (const float*)nullptr, (u16*)nullptr, 0,
                                              (const float*)nullptr, (u16*)nullptr, 0);
    gemm2_bf16<<<dim3(DIM / BN, 72), blk, 0, stream>>>(hbuf, cnts, wA, out);
  } else {
    gemm1_kernel<<<dim3(HID / BN, 72), blk, 0, stream>>>(x, cnts, w1, w3, hbuf);
    gemm2_kernel<<<dim3(DIM / BN, 72), blk, 0, stream>>>(hbuf, cnts, w2, out);
  }
  zero_pad_kernel<<<dim3(64), dim3(256), 0, stream>>>(cnts, out);
}